// Round 4
// baseline (151.003 us; speedup 1.0000x reference)
//
#include <hip/hip_runtime.h>

// Sinkhorn top-k, sorted-value domain, linear scaling iteration x <- 1/(Mx).
// R4: WW 44->36 so K (4x36) + window (36) + accs fit the 256 arch-VGPR file
// -- eliminates the AGPR round-trip that R3's VGPR_Count=128 exposed, and
// cuts fmacs/app 176->144. Balanced +-16 index radius: edge ~2.3e-3,
// predicted absmax ~(edge)^2 ~ 5e-6 (law fit on WW=52->9e-13, WW=44->5.6e-9).

#define N      512
#define BATCH  16
#define KTOP   50
#define WW     36          // window floats per lane (radius +-16, balanced)
#define NW     (WW / 4)    // 9 float4 reads
#define NAPPS  200         // 100 iterations x (col + row normalize) - exact iterate
#define COEF   1442.6950408889634f   // log2(e) / EPSILON, EPSILON = 1e-3

__global__ __launch_bounds__(128, 1)
void sinkhorn_topk_kernel(const float* __restrict__ scores,
                          float* __restrict__ out) {
    __shared__ __align__(16) float tv[N];   // sorted values, descending
    __shared__ int                 ti[N];   // original index of each rank
    __shared__ __align__(16) float xA[N];   // scaling vector, double buffered
    __shared__ __align__(16) float xB[N];

    const int tid = threadIdx.x;            // 0..127
    const int b   = blockIdx.x;

    // load 4 contiguous scores per thread
    ((float4*)tv)[tid] = ((const float4*)(scores + b * N))[tid];
    ((int4*)ti)[tid]   = make_int4(4 * tid, 4 * tid + 1, 4 * tid + 2, 4 * tid + 3);
    __syncthreads();

    // ---- bitonic sort, descending; 128 threads x 2 compare-exchanges/step ----
    for (int k = 2; k <= N; k <<= 1) {
        for (int j = k >> 1; j > 0; j >>= 1) {
#pragma unroll
            for (int e = 0; e < 2; ++e) {
                int q = tid + e * 128;                    // pair id, 0..255
                int i = ((q & ~(j - 1)) << 1) | (q & (j - 1));
                int p = i | j;
                float va = tv[i], vb = tv[p];
                bool up = ((i & k) == 0);
                bool sw = up ? (va < vb) : (va > vb);
                if (sw) {
                    tv[i] = vb; tv[p] = va;
                    int t_ = ti[i]; ti[i] = ti[p]; ti[p] = t_;
                }
            }
            __syncthreads();
        }
    }

    // ---- per-lane rows 4*tid .. 4*tid+3; shared aligned window ----
    const int r0 = 4 * tid;
    int wb = r0 - 16;                        // 4-aligned by construction
    wb = wb < 0 ? 0 : wb;
    wb = wb > (N - WW) ? (N - WW) : wb;

    float trow[4];
#pragma unroll
    for (int r = 0; r < 4; ++r) trow[r] = tv[r0 + r];

    float K[4][WW];
#pragma unroll
    for (int m = 0; m < WW; ++m) {
        float s = tv[wb + m];
#pragma unroll
        for (int r = 0; r < 4; ++r) {
            float d = trow[r] - s;
            K[r][m] = exp2f(-COEF * d * d);  // exp(-d^2/eps)
        }
    }

    ((float4*)xA)[tid] = make_float4(1.f, 1.f, 1.f, 1.f);
    __syncthreads();

    // ---- 200 applications of x <- 1/(M x) ----
    float* xr = xA;
    float* xw = xB;
    for (int t = 0; t < NAPPS; ++t) {
        const float4* wv = (const float4*)(xr + wb);
        float acc[4][4];
#pragma unroll
        for (int r = 0; r < 4; ++r)
#pragma unroll
            for (int c = 0; c < 4; ++c) acc[r][c] = 0.f;

#pragma unroll
        for (int m = 0; m < NW; ++m) {
            float4 w = wv[m];
#pragma unroll
            for (int r = 0; r < 4; ++r) {
                acc[r][0] += K[r][4 * m + 0] * w.x;
                acc[r][1] += K[r][4 * m + 1] * w.y;
                acc[r][2] += K[r][4 * m + 2] * w.z;
                acc[r][3] += K[r][4 * m + 3] * w.w;
            }
        }
        float4 o;
        o.x = __builtin_amdgcn_rcpf((acc[0][0] + acc[0][1]) + (acc[0][2] + acc[0][3]));
        o.y = __builtin_amdgcn_rcpf((acc[1][0] + acc[1][1]) + (acc[1][2] + acc[1][3]));
        o.z = __builtin_amdgcn_rcpf((acc[2][0] + acc[2][1]) + (acc[2][2] + acc[2][3]));
        o.w = __builtin_amdgcn_rcpf((acc[3][0] + acc[3][1]) + (acc[3][2] + acc[3][3]));
        ((float4*)xw)[tid] = o;              // rows 4t..4t+3 contiguous
        __syncthreads();
        float* tmp = xr; xr = xw; xw = tmp;
    }
    // xr = r (app 200), xw = c (app 199)

    // ---- epilogue: out_row = r_a * sum_{j<K} M_{a,j} c_j, scatter by rank ----
    float acc[4] = {0.f, 0.f, 0.f, 0.f};
#pragma unroll
    for (int m = 0; m < WW; ++m) {
        int col = wb + m;
        if (col < KTOP) {
            float cc = xw[col];
#pragma unroll
            for (int r = 0; r < 4; ++r) acc[r] += K[r][m] * cc;
        }
    }
#pragma unroll
    for (int r = 0; r < 4; ++r)
        out[b * N + ti[r0 + r]] = xr[r0 + r] * acc[r];
}

extern "C" void kernel_launch(void* const* d_in, const int* in_sizes, int n_in,
                              void* d_out, int out_size, void* d_ws, size_t ws_size,
                              hipStream_t stream) {
    const float* scores = (const float*)d_in[0];
    float* out = (float*)d_out;
    sinkhorn_topk_kernel<<<dim3(BATCH), dim3(128), 0, stream>>>(scores, out);
}

// Round 6
// 141.138 us; speedup vs baseline: 1.0699x; 1.0699x over previous
//
#include <hip/hip_runtime.h>

// Sinkhorn top-k, sorted-value domain, linear iteration x <- 1/(Mx).
// R6 = R5 with the cvt_pkrtz type fixed (bit_cast __fp16x2 -> _Float16x2).
// fp16 storage for x and K, f32 accumulation via v_dot2_f32_f16.

#define N      512
#define BATCH  16
#define KTOP   50
#define WH     40          // window width in halves (floats), radius >= +-16
#define NH2    (WH / 2)    // 20 half2 per row window
#define NAPPS  200         // 100 iterations x (col + row) - exact iterate count
#define COEF   1442.6950408889634f   // log2(e) / EPSILON, EPSILON = 1e-3

typedef _Float16 h2 __attribute__((ext_vector_type(2)));

static __device__ __forceinline__ h2 pack2(float a, float b) {
    return __builtin_bit_cast(h2, __builtin_amdgcn_cvt_pkrtz(a, b));
}

__global__ __launch_bounds__(128, 1)
void sinkhorn_topk_kernel(const float* __restrict__ scores,
                          float* __restrict__ out) {
    __shared__ __align__(16) float    tv[N];   // sorted values, descending
    __shared__ int                    ti[N];   // original index of each rank
    __shared__ __align__(16) _Float16 xA[N];   // scaling vector (fp16), dbuf
    __shared__ __align__(16) _Float16 xB[N];

    const int tid = threadIdx.x;               // 0..127
    const int b   = blockIdx.x;

    ((float4*)tv)[tid] = ((const float4*)(scores + b * N))[tid];
    ((int4*)ti)[tid]   = make_int4(4 * tid, 4 * tid + 1, 4 * tid + 2, 4 * tid + 3);
    __syncthreads();

    // ---- bitonic sort, descending; 128 threads x 2 compare-exchanges/step ----
    for (int k = 2; k <= N; k <<= 1) {
        for (int j = k >> 1; j > 0; j >>= 1) {
#pragma unroll
            for (int e = 0; e < 2; ++e) {
                int q = tid + e * 128;
                int i = ((q & ~(j - 1)) << 1) | (q & (j - 1));
                int p = i | j;
                float va = tv[i], vb = tv[p];
                bool up = ((i & k) == 0);
                bool sw = up ? (va < vb) : (va > vb);
                if (sw) {
                    tv[i] = vb; tv[p] = va;
                    int t_ = ti[i]; ti[i] = ti[p]; ti[p] = t_;
                }
            }
            __syncthreads();
        }
    }

    // ---- rows 4*tid..4*tid+3; window base 8-float aligned (16B in halves) ----
    const int r0 = 4 * tid;
    int wb = (r0 - 16) & ~7;                   // 16B-aligned in fp16 domain
    wb = wb < 0 ? 0 : wb;
    wb = wb > (N - WH) ? (N - WH) : wb;

    float trow[4];
#pragma unroll
    for (int r = 0; r < 4; ++r) trow[r] = tv[r0 + r];

    h2 K2[4][NH2];                             // fp16 kernel band, 80 VGPRs
#pragma unroll
    for (int m = 0; m < NH2; ++m) {
        float s0 = tv[wb + 2 * m];
        float s1 = tv[wb + 2 * m + 1];
#pragma unroll
        for (int r = 0; r < 4; ++r) {
            float d0 = trow[r] - s0;
            float d1 = trow[r] - s1;
            K2[r][m] = pack2(exp2f(-COEF * d0 * d0), exp2f(-COEF * d1 * d1));
        }
    }

    ((uint2*)xA)[tid] = make_uint2(0x3C003C00u, 0x3C003C00u);  // x = 1.0h
    __syncthreads();

    // ---- 200 applications of x <- 1/(M x) ----
    _Float16* xr = xA;
    _Float16* xw = xB;
    for (int t = 0; t < NAPPS; ++t) {
        const uint4* wv = (const uint4*)(xr + wb);   // 5 x ds_read_b128
        float acc[4] = {0.f, 0.f, 0.f, 0.f};
#pragma unroll
        for (int m = 0; m < WH / 8; ++m) {
            uint4 w = wv[m];
            h2 w0 = __builtin_bit_cast(h2, w.x);
            h2 w1 = __builtin_bit_cast(h2, w.y);
            h2 w2 = __builtin_bit_cast(h2, w.z);
            h2 w3 = __builtin_bit_cast(h2, w.w);
#pragma unroll
            for (int r = 0; r < 4; ++r) {
                acc[r] = __builtin_amdgcn_fdot2(K2[r][4 * m + 0], w0, acc[r], false);
                acc[r] = __builtin_amdgcn_fdot2(K2[r][4 * m + 1], w1, acc[r], false);
                acc[r] = __builtin_amdgcn_fdot2(K2[r][4 * m + 2], w2, acc[r], false);
                acc[r] = __builtin_amdgcn_fdot2(K2[r][4 * m + 3], w3, acc[r], false);
            }
        }
        h2 p01 = pack2(__builtin_amdgcn_rcpf(acc[0]), __builtin_amdgcn_rcpf(acc[1]));
        h2 p23 = pack2(__builtin_amdgcn_rcpf(acc[2]), __builtin_amdgcn_rcpf(acc[3]));
        ((uint2*)xw)[tid] = make_uint2(__builtin_bit_cast(unsigned, p01),
                                       __builtin_bit_cast(unsigned, p23));
        __syncthreads();
        _Float16* tmp = xr; xr = xw; xw = tmp;
    }
    // xr = r (app 200), xw = c (app 199)

    // ---- epilogue: out_row = r_a * sum_{j<K} M_{a,j} c_j, scatter by rank ----
    float acc[4] = {0.f, 0.f, 0.f, 0.f};
#pragma unroll
    for (int m = 0; m < WH; ++m) {
        int col = wb + m;
        if (col < KTOP) {
            float cc = (float)xw[col];
#pragma unroll
            for (int r = 0; r < 4; ++r) {
                h2 kk = K2[r][m / 2];
                float kv = (float)((m & 1) ? kk[1] : kk[0]);
                acc[r] += kv * cc;
            }
        }
    }
#pragma unroll
    for (int r = 0; r < 4; ++r)
        out[b * N + ti[r0 + r]] = (float)xr[r0 + r] * acc[r];
}

extern "C" void kernel_launch(void* const* d_in, const int* in_sizes, int n_in,
                              void* d_out, int out_size, void* d_ws, size_t ws_size,
                              hipStream_t stream) {
    const float* scores = (const float*)d_in[0];
    float* out = (float*)d_out;
    sinkhorn_topk_kernel<<<dim3(BATCH), dim3(128), 0, stream>>>(scores, out);
}